// Round 4
// baseline (965.593 us; speedup 1.0000x reference)
//
#include <hip/hip_runtime.h>
#include <math.h>

#define B_ 16
#define N_ 256
#define L_ 32
#define NN_ (N_*N_)          // 65536
#define NNL_ (NN_*L_)        // 2097152 elements per batch
#define ANN_ (B_*NN_)        // 1048576
#define POTS_OFF 4096        // float offset where big arrays start
#define NEGINF -1.0e30f
#define LOG2E_F 1.4426950408889634f
#define LN2_F   0.6931471805599453f

// Fast base-2 transcendentals (v_exp_f32 / v_log_f32). Math verified r2/r3.
#if __has_builtin(__builtin_amdgcn_exp2f)
#define EX2(x) __builtin_amdgcn_exp2f(x)
#else
#define EX2(x) exp2f(x)
#endif
#if __has_builtin(__builtin_amdgcn_logf)
#define LG2(x) __builtin_amdgcn_logf(x)
#else
#define LG2(x) log2f(x)
#endif

// ws float layout (float* W = (float*)d_ws):
//   [0 .. 2048)  : 1024 doubles — stats partials [B][32][2]
//   [2048..2080) : stats (mean, invstd) per batch
//   W + POTS_OFF + k*ANN_:
//     0: pot1 (start-major, log2 units)   1: sbar (start-major, nat units)
//     2: pot2 (log2)   3: pot3 (log2)
//     4: EG_ev p0 (end-major chart)  5: EG_h p0  6: SG_h p0 (start-major h)
//     7: EG p1   8: EG p2
//   W + POTS_OFF + 9*ANN_: zres[64]
//
// r3-verified structure: 48 blocks x 1024 threads. LEFT ev chart in LDS
// (triangular start-major, granule-XOR swizzled, ds_read_b128); RIGHT ev (+h
// both sides for p0) from global end-major rows (contiguous runs, L2-hot).
// r4: 1-deep software pipeline in the granule loop (issue next granule's
// loads before computing current) + full/tail split (masking out of hot loop).

// ---------------- kernel 1a: per-batch sum/sumsq partials ----------------
__global__ void stats_partial(const float* __restrict__ lp, double* __restrict__ part) {
    int blk = blockIdx.x;            // 0..511 = B*32
    int b = blk >> 5, seg = blk & 31;
    const float4* p4 = (const float4*)(lp + (size_t)b * NNL_ + (size_t)seg * (NNL_ / 32));
    double s = 0.0, ss = 0.0;
    for (int idx = threadIdx.x; idx < (NNL_ / 32 / 4); idx += 256) {
        float4 v = p4[idx];
        s  += (double)v.x + (double)v.y + (double)v.z + (double)v.w;
        ss += (double)v.x * v.x + (double)v.y * v.y + (double)v.z * v.z + (double)v.w * v.w;
    }
    __shared__ double sh0[256], sh1[256];
    sh0[threadIdx.x] = s; sh1[threadIdx.x] = ss;
    __syncthreads();
    for (int off = 128; off > 0; off >>= 1) {
        if (threadIdx.x < off) {
            sh0[threadIdx.x] += sh0[threadIdx.x + off];
            sh1[threadIdx.x] += sh1[threadIdx.x + off];
        }
        __syncthreads();
    }
    if (threadIdx.x == 0) { part[blk * 2] = sh0[0]; part[blk * 2 + 1] = sh1[0]; }
}

// ---------------- kernel 1b: finalize mean/invstd ----------------
__global__ void stats_final(const double* __restrict__ part, float* __restrict__ stats) {
    int b = threadIdx.x;
    if (b >= B_) return;
    double s = 0.0, ss = 0.0;
    for (int k = 0; k < 32; ++k) { s += part[(b * 32 + k) * 2]; ss += part[(b * 32 + k) * 2 + 1]; }
    double n = (double)NNL_;
    double mean = s / n;
    double var = (ss - s * s / n) / (n - 1.0);
    stats[b * 2]     = (float)mean;
    stats[b * 2 + 1] = (float)(1.0 / sqrt(var));
}

// ---------------- kernel 2: label-lse -> span potentials ----------------
__global__ __launch_bounds__(256)
void pots_kernel(const float* __restrict__ lp, const float* __restrict__ evm,
                 const float* __restrict__ stats, float* __restrict__ W) {
    int t = blockIdx.x * 256 + threadIdx.x;     // 0 .. B*NN-1
    int b = t >> 16;
    int rem = t & (NN_ - 1);
    int i = rem >> 8;
    int w = rem & (N_ - 1);
    if (i + w >= N_) return;
    int j = i + w;
    const float4* xp = (const float4*)(lp  + ((size_t)(b * NN_ + i * N_ + j) << 5));
    const float4* ep = (const float4*)(evm + ((size_t)(b * NN_ + i * N_ + j) << 5));
    float mean = stats[b * 2], invstd = stats[b * 2 + 1];
    float m1 = NEGINF, s1 = 0.f, n1 = 0.f;
    float m2 = NEGINF, s2 = 0.f;
    float m3 = NEGINF, s3 = 0.f;
#pragma unroll
    for (int c = 0; c < 8; ++c) {
        float4 xv = xp[c];
        float4 em = ep[c];
        float x0 = (xv.x - mean) * invstd, x1 = (xv.y - mean) * invstd;
        float x2 = (xv.z - mean) * invstd, x3 = (xv.w - mean) * invstd;
        {
            float cm = fmaxf(fmaxf(x0, x1), fmaxf(x2, x3));
            float nm = fmaxf(m1, cm);
            float sc = __expf(m1 - nm);
            float e0 = __expf(x0 - nm), e1 = __expf(x1 - nm);
            float e2 = __expf(x2 - nm), e3 = __expf(x3 - nm);
            s1 = s1 * sc + (e0 + e1 + e2 + e3);
            n1 = n1 * sc + (e0 * x0 + e1 * x1 + e2 * x2 + e3 * x3);
            m1 = nm;
        }
        {
            float y0 = x0 + __logf(fmaf(em.x, 0.9f, 0.1f) + 1e-10f);
            float y1 = x1 + __logf(fmaf(em.y, 0.9f, 0.1f) + 1e-10f);
            float y2 = x2 + __logf(fmaf(em.z, 0.9f, 0.1f) + 1e-10f);
            float y3 = x3 + __logf(fmaf(em.w, 0.9f, 0.1f) + 1e-10f);
            float cm = fmaxf(fmaxf(y0, y1), fmaxf(y2, y3));
            float nm = fmaxf(m2, cm);
            float sc = __expf(m2 - nm);
            s2 = s2 * sc + __expf(y0 - nm) + __expf(y1 - nm) + __expf(y2 - nm) + __expf(y3 - nm);
            m2 = nm;
        }
        {
            float z0 = fmaf(em.x, 1e6f, x0 - 1e6f);
            float z1 = fmaf(em.y, 1e6f, x1 - 1e6f);
            float z2 = fmaf(em.z, 1e6f, x2 - 1e6f);
            float z3 = fmaf(em.w, 1e6f, x3 - 1e6f);
            float cm = fmaxf(fmaxf(z0, z1), fmaxf(z2, z3));
            float nm = fmaxf(m3, cm);
            float sc = __expf(m3 - nm);
            s3 = s3 * sc + __expf(z0 - nm) + __expf(z1 - nm) + __expf(z2 - nm) + __expf(z3 - nm);
            m3 = nm;
        }
    }
    int o = b * NN_ + i * N_ + w;                // START-major layout
    W[POTS_OFF + 0 * ANN_ + o] = (m1 + __logf(s1)) * LOG2E_F;
    W[POTS_OFF + 1 * ANN_ + o] = n1 / s1;
    W[POTS_OFF + 2 * ANN_ + o] = (m2 + __logf(s2)) * LOG2E_F;
    W[POTS_OFF + 3 * ANN_ + o] = (m3 + __logf(s3)) * LOG2E_F;
}

// ---------------- LDS triangular chart addressing ----------------
// Start-major: row i holds widths u = 0..(255-i), capacity padded to 32-float
// (8-granule) multiples: cap32(i) = 32*(8 - (i>>5)). Total = 36864 floats
// (144 KB). Swizzle: granule index XOR (i&7) — stays in-row because capacity
// is a multiple of 8 granules; keeps 16B alignment for ds_read_b128.
__device__ __forceinline__ int lds_base(int i) {
    int a = i >> 5, c = i & 31;
    return ((8 * a - ((a * (a - 1)) >> 1)) << 10) + ((c * (8 - a)) << 5);
}
__device__ __forceinline__ int lds_addr(int i, int u) {
    return lds_base(i) + ((((u >> 2) ^ (i & 7)) << 2) | (u & 3));
}

// unaligned (4B-aligned) 16B global load
__device__ __forceinline__ float4 ld4u(const float* p) {
    float4 v; __builtin_memcpy(&v, p, 16); return v;
}

// ---------------- one width step ----------------
// group = cell (G = 2^LOGG consecutive tids). Lane l owns granules mu = l,
// l+G, ...; full granules (all 4 splits valid) in the pipelined hot loop,
// masked tail granule handled once by its owner lane. 1-deep lookahead:
// next granule's loads are issued before computing the current one.
template <bool EXPM, int LOGG>
__device__ __forceinline__ void stepw(
    float* __restrict__ SL,
    const float* __restrict__ pot, const float* __restrict__ sbr,
    float* __restrict__ EGe, float* __restrict__ EGh, float* __restrict__ SGh,
    const int w, const int cells, const int tid)
{
    constexpr int G = 1 << LOGG;
    const int group = tid >> LOGG;
    const int l = tid & (G - 1);
    if (group >= cells) return;
    const int i = group;
    const int j = i + w;
    const int ib = lds_base(i);
    const int isw = i & 7;
    const float* egE = EGe + j * N_;
    const float* egH = EGh + j * N_;
    const float* sgH = SGh + i * N_;
    // epilogue inputs: issue early, consume late
    const float pw = pot[i * N_ + w];
    float sb = 0.f;
    if constexpr (EXPM) sb = sbr[i * N_ + w];

    const int F = w >> 2;        // full granules
    const int r = w & 3;         // tail valid count (0 => no tail)

    float m = NEGINF, s = 0.f, n = 0.f;

    // ---- pipelined hot loop over full granules ----
    int mu = l;
    bool have = (mu < F);
    float4 Lc, Rc, Hlc, Hrc;
    if (have) {
        Lc = *(const float4*)&SL[ib + ((mu ^ isw) << 2)];
        Rc = ld4u(egE + (w - 4 - (mu << 2)));
        if constexpr (EXPM) {
            Hlc = *(const float4*)(sgH + (mu << 2));
            Hrc = ld4u(egH + (w - 4 - (mu << 2)));
        }
    }
    while (have) {
        const int mun = mu + G;
        const bool hn = (mun < F);
        float4 Ln, Rn, Hln, Hrn;
        if (hn) {
            Ln = *(const float4*)&SL[ib + ((mun ^ isw) << 2)];
            Rn = ld4u(egE + (w - 4 - (mun << 2)));
            if constexpr (EXPM) {
                Hln = *(const float4*)(sgH + (mun << 2));
                Hrn = ld4u(egH + (w - 4 - (mun << 2)));
            }
        }
        // compute current granule (splits u = 4mu .. 4mu+3, all valid)
        {
            float e0 = Lc.x + Rc.w;
            float e1 = Lc.y + Rc.z;
            float e2 = Lc.z + Rc.y;
            float e3 = Lc.w + Rc.x;
            float cm = fmaxf(fmaxf(e0, e1), fmaxf(e2, e3));
            float nm = fmaxf(m, cm);
            float sc = EX2(m - nm);
            float E0 = EX2(e0 - nm), E1 = EX2(e1 - nm);
            float E2 = EX2(e2 - nm), E3 = EX2(e3 - nm);
            s = s * sc + ((E0 + E1) + (E2 + E3));
            if constexpr (EXPM) {
                float h0 = Hlc.x + Hrc.w, h1 = Hlc.y + Hrc.z;
                float h2 = Hlc.z + Hrc.y, h3 = Hlc.w + Hrc.x;
                n = n * sc + ((E0 * h0 + E1 * h1) + (E2 * h2 + E3 * h3));
            }
            m = nm;
        }
        Lc = Ln; Rc = Rn;
        if constexpr (EXPM) { Hlc = Hln; Hrc = Hrn; }
        mu = mun; have = hn;
    }

    // ---- masked tail granule (index F, r valid splits), one owner lane ----
    if (r && l == (F & (G - 1))) {
        const int u0 = F << 2;
        const float4 Lv = *(const float4*)&SL[ib + ((F ^ isw) << 2)];
        const float4 Rv = ld4u(egE + (w - 4 - u0));   // starts r-4 before row j:
        float e0 = Lv.x + Rv.w;                        // row j-1 tail garbage,
        float e1 = Lv.y + Rv.z;                        // masked below
        float e2 = Lv.z + Rv.y;
        float e3 = NEGINF;
        if (r < 2) e1 = NEGINF;
        if (r < 3) e2 = NEGINF;
        float cm = fmaxf(fmaxf(e0, e1), e2);
        float nm = fmaxf(m, cm);
        float sc = EX2(m - nm);
        float E0 = EX2(e0 - nm), E1 = EX2(e1 - nm);
        float E2 = EX2(e2 - nm), E3 = EX2(e3 - nm);
        s = s * sc + ((E0 + E1) + (E2 + E3));
        if constexpr (EXPM) {
            const float4 Hl = *(const float4*)(sgH + u0);
            const float4 Hr = ld4u(egH + (w - 4 - u0));
            float h0 = Hl.x + Hr.w, h1 = Hl.y + Hr.z, h2 = Hl.z + Hr.y;
            if (r < 2) h1 = 0.f;        // garbage could be Inf/NaN: E*h -> NaN
            if (r < 3) h2 = 0.f;
            n = n * sc + ((E0 * h0 + E1 * h1) + E2 * h2);
        }
        m = nm;
    }

    // merge across the G lanes of the group (consecutive tids, within a wave)
#pragma unroll
    for (int k = 1; k < G; k <<= 1) {
        float mo = __shfl_xor(m, k);
        float so = __shfl_xor(s, k);
        float no = 0.f;
        if constexpr (EXPM) no = __shfl_xor(n, k);
        float nm = fmaxf(m, mo);
        float a  = EX2(m - nm), bb = EX2(mo - nm);
        s = s * a + so * bb;
        if constexpr (EXPM) n = n * a + no * bb;
        m = nm;
    }
    if (l == 0) {
        float v = pw + m + LG2(s);
        SL[lds_addr(i, w)] = v;
        EGe[j * N_ + w] = v;
        if constexpr (EXPM) {
            float hv = sb + n / s;
            SGh[i * N_ + w] = hv;
            EGh[j * N_ + w] = hv;
        }
    }
}

template <bool EXPM>
__device__ __forceinline__ void cky_loop(
    float* __restrict__ SL,
    const float* __restrict__ pot, const float* __restrict__ sbr,
    float* __restrict__ EGe, float* __restrict__ EGh, float* __restrict__ SGh,
    const int len, const int tid)
{
    // width-0 diagonal
    for (int i = tid; i < len; i += 1024) {
        float v = pot[i * N_];
        SL[lds_addr(i, 0)] = v;
        EGe[i * N_] = v;
        if constexpr (EXPM) { float h0 = sbr[i * N_]; SGh[i * N_] = h0; EGh[i * N_] = h0; }
    }
    __syncthreads();
    for (int w = 1; w < len; ++w) {
        const int cells = len - w;
        if (cells > 128)      stepw<EXPM, 2>(SL, pot, sbr, EGe, EGh, SGh, w, cells, tid);
        else if (cells > 64)  stepw<EXPM, 3>(SL, pot, sbr, EGe, EGh, SGh, w, cells, tid);
        else if (cells > 32)  stepw<EXPM, 4>(SL, pot, sbr, EGe, EGh, SGh, w, cells, tid);
        else if (cells > 16)  stepw<EXPM, 5>(SL, pot, sbr, EGe, EGh, SGh, w, cells, tid);
        else                  stepw<EXPM, 6>(SL, pot, sbr, EGe, EGh, SGh, w, cells, tid);
        __syncthreads();
    }
}

// ---------------- kernel 3: all three CKY inside passes ----------------
__global__ __launch_bounds__(1024, 1)
void cky_all(float* __restrict__ W, const int* __restrict__ lengths) {
    __shared__ float SL[36864];           // 144 KB triangular chart
    const int bx = blockIdx.x;
    const int p = bx >> 4, b = bx & 15;
    const int tid = threadIdx.x;
    int len = lengths[b];
    if (len < 1) len = 1;
    if (len > N_) len = N_;
    float* zres = W + POTS_OFF + 9 * ANN_;

    if (p == 0) {
        const float* pot = W + POTS_OFF + 0 * ANN_ + b * NN_;
        const float* sbr = W + POTS_OFF + 1 * ANN_ + b * NN_;
        float* EGe = W + POTS_OFF + 4 * ANN_ + b * NN_;
        float* EGh = W + POTS_OFF + 5 * ANN_ + b * NN_;
        float* SGh = W + POTS_OFF + 6 * ANN_ + b * NN_;
        cky_loop<true>(SL, pot, sbr, EGe, EGh, SGh, len, tid);
        if (tid == 0) {
            zres[b]      = SL[lds_addr(0, len - 1)];   // logZ_full (log2 units)
            zres[48 + b] = SGh[len - 1];               // E[sum sbar] (nat units)
        }
    } else {
        const float* pot = W + POTS_OFF + (p == 1 ? 2 : 3) * ANN_ + b * NN_;
        float* EGe = W + POTS_OFF + (p == 1 ? 7 : 8) * ANN_ + b * NN_;
        cky_loop<false>(SL, pot, nullptr, EGe, nullptr, nullptr, len, tid);
        if (tid == 0) zres[p * 16 + b] = SL[lds_addr(0, len - 1)];
    }
}

// ---------------- kernel 4: combine outputs ----------------
__global__ void combine_kernel(const float* __restrict__ W, float* __restrict__ out) {
    int b = threadIdx.x;
    if (b >= B_) return;
    const float* zres = W + POTS_OFF + 9 * ANN_;
    float zf = zres[b], zs = zres[16 + b], zp = zres[32 + b], hr = zres[48 + b];
    out[b]          = (zp - zf) * LN2_F;   // log_prob
    out[16 + b]     = (zs - zf) * LN2_F;   // log_prob_smooth
    out[32 + b]     = zf * LN2_F - hr;     // entropy = z_full - E[sum sbar]
}

extern "C" void kernel_launch(void* const* d_in, const int* in_sizes, int n_in,
                              void* d_out, int out_size, void* d_ws, size_t ws_size,
                              hipStream_t stream) {
    const float* lp      = (const float*)d_in[0];
    // d_in[1] (mask) is unused by the reference
    const int*   lengths = (const int*)d_in[2];
    const float* evm     = (const float*)d_in[3];
    float*  W    = (float*)d_ws;
    double* part = (double*)d_ws;
    float*  stats = W + 2048;
    float*  out  = (float*)d_out;

    stats_partial<<<B_ * 32, 256, 0, stream>>>(lp, part);
    stats_final<<<1, 64, 0, stream>>>(part, stats);
    pots_kernel<<<(B_ * NN_) / 256, 256, 0, stream>>>(lp, evm, stats, W);
    cky_all<<<3 * B_, 1024, 0, stream>>>(W, lengths);
    combine_kernel<<<1, 64, 0, stream>>>(W, out);
}

// Round 5
// 910.688 us; speedup vs baseline: 1.0603x; 1.0603x over previous
//
#include <hip/hip_runtime.h>
#include <math.h>

#define B_ 16
#define N_ 256
#define L_ 32
#define NN_ (N_*N_)          // 65536
#define NNL_ (NN_*L_)        // 2097152 elements per batch
#define ANN_ (B_*NN_)        // 1048576
#define POTS_OFF 4096        // float offset where big arrays start
#define NEGINF -1.0e30f
#define LOG2E_F 1.4426950408889634f
#define LN2_F   0.6931471805599453f

// Fast base-2 transcendentals (v_exp_f32 / v_log_f32). Math verified r2/r3.
#if __has_builtin(__builtin_amdgcn_exp2f)
#define EX2(x) __builtin_amdgcn_exp2f(x)
#else
#define EX2(x) exp2f(x)
#endif
#if __has_builtin(__builtin_amdgcn_logf)
#define LG2(x) __builtin_amdgcn_logf(x)
#else
#define LG2(x) log2f(x)
#endif

// ws float layout (float* W = (float*)d_ws):
//   [0 .. 2048)  : 1024 doubles — stats partials [B][32][2]
//   [2048..2080) : stats (mean, invstd) per batch
//   W + POTS_OFF + k*ANN_:
//     0: pot1 (start-major, log2 units)   1: sbar (start-major, nat units)
//     2: pot2 (log2)   3: pot3 (log2)
//     4-5: EG2 p0 — float2 (ev,h) END-major chart
//     6: SG_h p0 (start-major h)
//     7: EG p1   8: EG p2
//   W + POTS_OFF + 9*ANN_: zres[64]
//
// r3-verified structure (574us): 48 blocks x 1024 threads. LEFT ev chart in
// LDS (triangular start-major, granule-XOR swizzled, ds_read_b128); RIGHT
// operands from global end-major rows (contiguous runs, L2-hot). One
// __syncthreads per width step. r4's explicit while-loop pipeline REGRESSED
// (630us, +12 VGPR) — compiler schedules the plain for-loop better; reverted.
// r5: unroll-2 single-rescale inner loop (halves rescale exp2s + serial
// chain) + p0 (ev,h) interleaved float2 end-major (one row window instead
// of two separate right-side streams).

// ---------------- kernel 1a: per-batch sum/sumsq partials ----------------
__global__ void stats_partial(const float* __restrict__ lp, double* __restrict__ part) {
    int blk = blockIdx.x;            // 0..511 = B*32
    int b = blk >> 5, seg = blk & 31;
    const float4* p4 = (const float4*)(lp + (size_t)b * NNL_ + (size_t)seg * (NNL_ / 32));
    double s = 0.0, ss = 0.0;
    for (int idx = threadIdx.x; idx < (NNL_ / 32 / 4); idx += 256) {
        float4 v = p4[idx];
        s  += (double)v.x + (double)v.y + (double)v.z + (double)v.w;
        ss += (double)v.x * v.x + (double)v.y * v.y + (double)v.z * v.z + (double)v.w * v.w;
    }
    __shared__ double sh0[256], sh1[256];
    sh0[threadIdx.x] = s; sh1[threadIdx.x] = ss;
    __syncthreads();
    for (int off = 128; off > 0; off >>= 1) {
        if (threadIdx.x < off) {
            sh0[threadIdx.x] += sh0[threadIdx.x + off];
            sh1[threadIdx.x] += sh1[threadIdx.x + off];
        }
        __syncthreads();
    }
    if (threadIdx.x == 0) { part[blk * 2] = sh0[0]; part[blk * 2 + 1] = sh1[0]; }
}

// ---------------- kernel 1b: finalize mean/invstd ----------------
__global__ void stats_final(const double* __restrict__ part, float* __restrict__ stats) {
    int b = threadIdx.x;
    if (b >= B_) return;
    double s = 0.0, ss = 0.0;
    for (int k = 0; k < 32; ++k) { s += part[(b * 32 + k) * 2]; ss += part[(b * 32 + k) * 2 + 1]; }
    double n = (double)NNL_;
    double mean = s / n;
    double var = (ss - s * s / n) / (n - 1.0);
    stats[b * 2]     = (float)mean;
    stats[b * 2 + 1] = (float)(1.0 / sqrt(var));
}

// ---------------- kernel 2: label-lse -> span potentials ----------------
__global__ __launch_bounds__(256)
void pots_kernel(const float* __restrict__ lp, const float* __restrict__ evm,
                 const float* __restrict__ stats, float* __restrict__ W) {
    int t = blockIdx.x * 256 + threadIdx.x;     // 0 .. B*NN-1
    int b = t >> 16;
    int rem = t & (NN_ - 1);
    int i = rem >> 8;
    int w = rem & (N_ - 1);
    if (i + w >= N_) return;
    int j = i + w;
    const float4* xp = (const float4*)(lp  + ((size_t)(b * NN_ + i * N_ + j) << 5));
    const float4* ep = (const float4*)(evm + ((size_t)(b * NN_ + i * N_ + j) << 5));
    float mean = stats[b * 2], invstd = stats[b * 2 + 1];
    float m1 = NEGINF, s1 = 0.f, n1 = 0.f;
    float m2 = NEGINF, s2 = 0.f;
    float m3 = NEGINF, s3 = 0.f;
#pragma unroll
    for (int c = 0; c < 8; ++c) {
        float4 xv = xp[c];
        float4 em = ep[c];
        float x0 = (xv.x - mean) * invstd, x1 = (xv.y - mean) * invstd;
        float x2 = (xv.z - mean) * invstd, x3 = (xv.w - mean) * invstd;
        {
            float cm = fmaxf(fmaxf(x0, x1), fmaxf(x2, x3));
            float nm = fmaxf(m1, cm);
            float sc = __expf(m1 - nm);
            float e0 = __expf(x0 - nm), e1 = __expf(x1 - nm);
            float e2 = __expf(x2 - nm), e3 = __expf(x3 - nm);
            s1 = s1 * sc + (e0 + e1 + e2 + e3);
            n1 = n1 * sc + (e0 * x0 + e1 * x1 + e2 * x2 + e3 * x3);
            m1 = nm;
        }
        {
            float y0 = x0 + __logf(fmaf(em.x, 0.9f, 0.1f) + 1e-10f);
            float y1 = x1 + __logf(fmaf(em.y, 0.9f, 0.1f) + 1e-10f);
            float y2 = x2 + __logf(fmaf(em.z, 0.9f, 0.1f) + 1e-10f);
            float y3 = x3 + __logf(fmaf(em.w, 0.9f, 0.1f) + 1e-10f);
            float cm = fmaxf(fmaxf(y0, y1), fmaxf(y2, y3));
            float nm = fmaxf(m2, cm);
            float sc = __expf(m2 - nm);
            s2 = s2 * sc + __expf(y0 - nm) + __expf(y1 - nm) + __expf(y2 - nm) + __expf(y3 - nm);
            m2 = nm;
        }
        {
            float z0 = fmaf(em.x, 1e6f, x0 - 1e6f);
            float z1 = fmaf(em.y, 1e6f, x1 - 1e6f);
            float z2 = fmaf(em.z, 1e6f, x2 - 1e6f);
            float z3 = fmaf(em.w, 1e6f, x3 - 1e6f);
            float cm = fmaxf(fmaxf(z0, z1), fmaxf(z2, z3));
            float nm = fmaxf(m3, cm);
            float sc = __expf(m3 - nm);
            s3 = s3 * sc + __expf(z0 - nm) + __expf(z1 - nm) + __expf(z2 - nm) + __expf(z3 - nm);
            m3 = nm;
        }
    }
    int o = b * NN_ + i * N_ + w;                // START-major layout
    W[POTS_OFF + 0 * ANN_ + o] = (m1 + __logf(s1)) * LOG2E_F;
    W[POTS_OFF + 1 * ANN_ + o] = n1 / s1;
    W[POTS_OFF + 2 * ANN_ + o] = (m2 + __logf(s2)) * LOG2E_F;
    W[POTS_OFF + 3 * ANN_ + o] = (m3 + __logf(s3)) * LOG2E_F;
}

// ---------------- LDS triangular chart addressing ----------------
// Start-major: row i holds widths u = 0..(255-i), capacity padded to 32-float
// (8-granule) multiples: cap32(i) = 32*(8 - (i>>5)). Total = 36864 floats
// (144 KB). Swizzle: granule index XOR (i&7) — stays in-row because capacity
// is a multiple of 8 granules; keeps 16B alignment for ds_read_b128.
__device__ __forceinline__ int lds_base(int i) {
    int a = i >> 5, c = i & 31;
    return ((8 * a - ((a * (a - 1)) >> 1)) << 10) + ((c * (8 - a)) << 5);
}
__device__ __forceinline__ int lds_addr(int i, int u) {
    return lds_base(i) + ((((u >> 2) ^ (i & 7)) << 2) | (u & 3));
}

// unaligned (4B-aligned) 16B global load
__device__ __forceinline__ float4 ld4u(const float* p) {
    float4 v; __builtin_memcpy(&v, p, 16); return v;
}

// ---------------- one width step ----------------
// group = cell (G = 2^LOGG consecutive tids). Lane l owns granules mu = l,
// l+G, ... of full granules F = w>>2; hot loop processes TWO granules per
// iteration with a SINGLE online-softmax rescale (8 splits / rescale).
// p0 right side: (ev,h) float2 end-major rows — an 8-float window per
// granule covers both ev and h. Masked tail granule handled by owner lane.
template <bool EXPM, int LOGG>
__device__ __forceinline__ void stepw(
    float* __restrict__ SL,
    const float* __restrict__ pot, const float* __restrict__ sbr,
    float* __restrict__ EG,      // p0: float2 (ev,h) chart; p1/p2: float chart
    float* __restrict__ SGh,
    const int w, const int cells, const int tid)
{
    constexpr int G = 1 << LOGG;
    const int group = tid >> LOGG;
    const int l = tid & (G - 1);
    if (group >= cells) return;
    const int i = group;
    const int j = i + w;
    const int ib = lds_base(i);
    const int isw = i & 7;
    const float* egE = EG + (EXPM ? ((j * N_) << 1) : (j * N_));
    const float* sgH = SGh + i * N_;
    // epilogue inputs: issue early, consume late
    const float pw = pot[i * N_ + w];
    float sb = 0.f;
    if constexpr (EXPM) sb = sbr[i * N_ + w];

    const int F = w >> 2;        // full granules
    const int r = w & 3;         // tail valid count (0 => no tail)

    float m = NEGINF, s = 0.f, n = 0.f;

    int mu = l;
    // ---- hot loop: 2 granules, one rescale ----
    for (; mu + G < F; mu += 2 * G) {
        const int ua = mu << 2, ub = (mu + G) << 2;
        const float4 La = *(const float4*)&SL[ib + ((mu ^ isw) << 2)];
        const float4 Lb = *(const float4*)&SL[ib + (((mu + G) ^ isw) << 2)];
        float ea0, ea1, ea2, ea3, eb0, eb1, eb2, eb3;
        float ha0, ha1, ha2, ha3, hb0, hb1, hb2, hb3;
        if constexpr (EXPM) {
            const float4 Pa0 = ld4u(egE + ((w - 4 - ua) << 1));
            const float4 Pa1 = ld4u(egE + ((w - 4 - ua) << 1) + 4);
            const float4 Pb0 = ld4u(egE + ((w - 4 - ub) << 1));
            const float4 Pb1 = ld4u(egE + ((w - 4 - ub) << 1) + 4);
            const float4 Ha = *(const float4*)(sgH + ua);
            const float4 Hb = *(const float4*)(sgH + ub);
            ea0 = La.x + Pa1.z; ea1 = La.y + Pa1.x; ea2 = La.z + Pa0.z; ea3 = La.w + Pa0.x;
            eb0 = Lb.x + Pb1.z; eb1 = Lb.y + Pb1.x; eb2 = Lb.z + Pb0.z; eb3 = Lb.w + Pb0.x;
            ha0 = Ha.x + Pa1.w; ha1 = Ha.y + Pa1.y; ha2 = Ha.z + Pa0.w; ha3 = Ha.w + Pa0.y;
            hb0 = Hb.x + Pb1.w; hb1 = Hb.y + Pb1.y; hb2 = Hb.z + Pb0.w; hb3 = Hb.w + Pb0.y;
        } else {
            const float4 Ra = ld4u(egE + (w - 4 - ua));
            const float4 Rb = ld4u(egE + (w - 4 - ub));
            ea0 = La.x + Ra.w; ea1 = La.y + Ra.z; ea2 = La.z + Ra.y; ea3 = La.w + Ra.x;
            eb0 = Lb.x + Rb.w; eb1 = Lb.y + Rb.z; eb2 = Lb.z + Rb.y; eb3 = Lb.w + Rb.x;
        }
        float cma = fmaxf(fmaxf(ea0, ea1), fmaxf(ea2, ea3));
        float cmb = fmaxf(fmaxf(eb0, eb1), fmaxf(eb2, eb3));
        float nm = fmaxf(m, fmaxf(cma, cmb));
        float sc = EX2(m - nm);
        float A0 = EX2(ea0 - nm), A1 = EX2(ea1 - nm), A2 = EX2(ea2 - nm), A3 = EX2(ea3 - nm);
        float B0 = EX2(eb0 - nm), B1 = EX2(eb1 - nm), B2 = EX2(eb2 - nm), B3 = EX2(eb3 - nm);
        s = s * sc + (((A0 + A1) + (A2 + A3)) + ((B0 + B1) + (B2 + B3)));
        if constexpr (EXPM) {
            n = n * sc + (((A0 * ha0 + A1 * ha1) + (A2 * ha2 + A3 * ha3))
                        + ((B0 * hb0 + B1 * hb1) + (B2 * hb2 + B3 * hb3)));
        }
        m = nm;
    }
    // ---- leftover full granule (0 or 1 per lane) ----
    if (mu < F) {
        const int u0 = mu << 2;
        const float4 Lv = *(const float4*)&SL[ib + ((mu ^ isw) << 2)];
        float e0, e1, e2, e3, h0, h1, h2, h3;
        if constexpr (EXPM) {
            const float4 P0 = ld4u(egE + ((w - 4 - u0) << 1));
            const float4 P1 = ld4u(egE + ((w - 4 - u0) << 1) + 4);
            const float4 Hl = *(const float4*)(sgH + u0);
            e0 = Lv.x + P1.z; e1 = Lv.y + P1.x; e2 = Lv.z + P0.z; e3 = Lv.w + P0.x;
            h0 = Hl.x + P1.w; h1 = Hl.y + P1.y; h2 = Hl.z + P0.w; h3 = Hl.w + P0.y;
        } else {
            const float4 Rv = ld4u(egE + (w - 4 - u0));
            e0 = Lv.x + Rv.w; e1 = Lv.y + Rv.z; e2 = Lv.z + Rv.y; e3 = Lv.w + Rv.x;
        }
        float cm = fmaxf(fmaxf(e0, e1), fmaxf(e2, e3));
        float nm = fmaxf(m, cm);
        float sc = EX2(m - nm);
        float E0 = EX2(e0 - nm), E1 = EX2(e1 - nm), E2 = EX2(e2 - nm), E3 = EX2(e3 - nm);
        s = s * sc + ((E0 + E1) + (E2 + E3));
        if constexpr (EXPM)
            n = n * sc + ((E0 * h0 + E1 * h1) + (E2 * h2 + E3 * h3));
        m = nm;
    }
    // ---- masked tail granule (index F, r valid splits), one owner lane ----
    // Its 8/4-float window starts before row j (row j-1 tail garbage, j>=1
    // keeps it inside the array); invalid slots masked to NEGINF / h=0 so
    // Inf/NaN garbage cannot propagate (0*Inf would be NaN).
    if (r && l == (F & (G - 1))) {
        const int u0 = F << 2;
        const float4 Lv = *(const float4*)&SL[ib + ((F ^ isw) << 2)];
        float e0, e1, e2, h0 = 0.f, h1 = 0.f, h2 = 0.f;
        if constexpr (EXPM) {
            const float4 P0 = ld4u(egE + ((w - 4 - u0) << 1));
            const float4 P1 = ld4u(egE + ((w - 4 - u0) << 1) + 4);
            const float4 Hl = *(const float4*)(sgH + u0);
            e0 = Lv.x + P1.z; e1 = Lv.y + P1.x; e2 = Lv.z + P0.z;
            h0 = Hl.x + P1.w; h1 = Hl.y + P1.y; h2 = Hl.z + P0.w;
        } else {
            const float4 Rv = ld4u(egE + (w - 4 - u0));
            e0 = Lv.x + Rv.w; e1 = Lv.y + Rv.z; e2 = Lv.z + Rv.y;
        }
        if (r < 2) { e1 = NEGINF; h1 = 0.f; }
        if (r < 3) { e2 = NEGINF; h2 = 0.f; }
        float cm = fmaxf(fmaxf(e0, e1), e2);
        float nm = fmaxf(m, cm);
        float sc = EX2(m - nm);
        float E0 = EX2(e0 - nm), E1 = EX2(e1 - nm), E2 = EX2(e2 - nm);
        s = s * sc + ((E0 + E1) + E2);
        if constexpr (EXPM)
            n = n * sc + ((E0 * h0 + E1 * h1) + E2 * h2);
        m = nm;
    }

    // merge across the G lanes of the group (consecutive tids, within a wave)
#pragma unroll
    for (int k = 1; k < G; k <<= 1) {
        float mo = __shfl_xor(m, k);
        float so = __shfl_xor(s, k);
        float no = 0.f;
        if constexpr (EXPM) no = __shfl_xor(n, k);
        float nm = fmaxf(m, mo);
        float a  = EX2(m - nm), bb = EX2(mo - nm);
        s = s * a + so * bb;
        if constexpr (EXPM) n = n * a + no * bb;
        m = nm;
    }
    if (l == 0) {
        float v = pw + m + LG2(s);
        SL[lds_addr(i, w)] = v;
        if constexpr (EXPM) {
            float hv = sb + n / s;
            ((float2*)EG)[j * N_ + w] = make_float2(v, hv);
            SGh[i * N_ + w] = hv;
        } else {
            EG[j * N_ + w] = v;
        }
    }
}

template <bool EXPM>
__device__ __forceinline__ void cky_loop(
    float* __restrict__ SL,
    const float* __restrict__ pot, const float* __restrict__ sbr,
    float* __restrict__ EG, float* __restrict__ SGh,
    const int len, const int tid)
{
    // width-0 diagonal
    for (int i = tid; i < len; i += 1024) {
        float v = pot[i * N_];
        SL[lds_addr(i, 0)] = v;
        if constexpr (EXPM) {
            float h0 = sbr[i * N_];
            ((float2*)EG)[i * N_] = make_float2(v, h0);
            SGh[i * N_] = h0;
        } else {
            EG[i * N_] = v;
        }
    }
    __syncthreads();
    for (int w = 1; w < len; ++w) {
        const int cells = len - w;
        if (cells > 128)      stepw<EXPM, 2>(SL, pot, sbr, EG, SGh, w, cells, tid);
        else if (cells > 64)  stepw<EXPM, 3>(SL, pot, sbr, EG, SGh, w, cells, tid);
        else if (cells > 32)  stepw<EXPM, 4>(SL, pot, sbr, EG, SGh, w, cells, tid);
        else if (cells > 16)  stepw<EXPM, 5>(SL, pot, sbr, EG, SGh, w, cells, tid);
        else                  stepw<EXPM, 6>(SL, pot, sbr, EG, SGh, w, cells, tid);
        __syncthreads();
    }
}

// ---------------- kernel 3: all three CKY inside passes ----------------
__global__ __launch_bounds__(1024, 1)
void cky_all(float* __restrict__ W, const int* __restrict__ lengths) {
    __shared__ float SL[36864];           // 144 KB triangular chart
    const int bx = blockIdx.x;
    const int p = bx >> 4, b = bx & 15;
    const int tid = threadIdx.x;
    int len = lengths[b];
    if (len < 1) len = 1;
    if (len > N_) len = N_;
    float* zres = W + POTS_OFF + 9 * ANN_;

    if (p == 0) {
        const float* pot = W + POTS_OFF + 0 * ANN_ + b * NN_;
        const float* sbr = W + POTS_OFF + 1 * ANN_ + b * NN_;
        float* EG2 = W + POTS_OFF + 4 * ANN_ + b * (NN_ * 2);   // float2 chart
        float* SGh = W + POTS_OFF + 6 * ANN_ + b * NN_;
        cky_loop<true>(SL, pot, sbr, EG2, SGh, len, tid);
        if (tid == 0) {
            zres[b]      = SL[lds_addr(0, len - 1)];   // logZ_full (log2 units)
            zres[48 + b] = SGh[len - 1];               // E[sum sbar] (nat units)
        }
    } else {
        const float* pot = W + POTS_OFF + (p == 1 ? 2 : 3) * ANN_ + b * NN_;
        float* EG = W + POTS_OFF + (p == 1 ? 7 : 8) * ANN_ + b * NN_;
        cky_loop<false>(SL, pot, nullptr, EG, nullptr, len, tid);
        if (tid == 0) zres[p * 16 + b] = SL[lds_addr(0, len - 1)];
    }
}

// ---------------- kernel 4: combine outputs ----------------
__global__ void combine_kernel(const float* __restrict__ W, float* __restrict__ out) {
    int b = threadIdx.x;
    if (b >= B_) return;
    const float* zres = W + POTS_OFF + 9 * ANN_;
    float zf = zres[b], zs = zres[16 + b], zp = zres[32 + b], hr = zres[48 + b];
    out[b]          = (zp - zf) * LN2_F;   // log_prob
    out[16 + b]     = (zs - zf) * LN2_F;   // log_prob_smooth
    out[32 + b]     = zf * LN2_F - hr;     // entropy = z_full - E[sum sbar]
}

extern "C" void kernel_launch(void* const* d_in, const int* in_sizes, int n_in,
                              void* d_out, int out_size, void* d_ws, size_t ws_size,
                              hipStream_t stream) {
    const float* lp      = (const float*)d_in[0];
    // d_in[1] (mask) is unused by the reference
    const int*   lengths = (const int*)d_in[2];
    const float* evm     = (const float*)d_in[3];
    float*  W    = (float*)d_ws;
    double* part = (double*)d_ws;
    float*  stats = W + 2048;
    float*  out  = (float*)d_out;

    stats_partial<<<B_ * 32, 256, 0, stream>>>(lp, part);
    stats_final<<<1, 64, 0, stream>>>(part, stats);
    pots_kernel<<<(B_ * NN_) / 256, 256, 0, stream>>>(lp, evm, stats, W);
    cky_all<<<3 * B_, 1024, 0, stream>>>(W, lengths);
    combine_kernel<<<1, 64, 0, stream>>>(W, out);
}